// Round 8
// baseline (846.675 us; speedup 1.0000x reference)
//
#include <hip/hip_runtime.h>
#include <cmath>

#define DMODEL  1024
#define DINNER  2048
#define NHEADS  32
#define CONVDIM 2176
#define DPROJ   4256
#define VOCAB   50257
#define NBLK_V  400            // LM-head n-blocks (400*128 = 51200 >= VOCAB, %8==0)
#define CLEN    32
#define NCHUNK  32

typedef float f32x4 __attribute__((ext_vector_type(4)));
typedef float f32x2 __attribute__((ext_vector_type(2)));
typedef unsigned short u16;
typedef u16 u16x4 __attribute__((ext_vector_type(4)));
typedef u16 u16x8 __attribute__((ext_vector_type(8)));
typedef __bf16 bf16x8 __attribute__((ext_vector_type(8)));

__device__ __forceinline__ u16 f2bf(float f) {
  unsigned u = __builtin_bit_cast(unsigned, f);
  u += 0x7FFFu + ((u >> 16) & 1u);
  return (u16)(u >> 16);
}
__device__ __forceinline__ float silu_f(float x) { return x / (1.f + expf(-x)); }

__device__ __forceinline__ void gload16(const u16* g, u16* l) {
  __builtin_amdgcn_global_load_lds(
      (const __attribute__((address_space(1))) void*)g,
      (__attribute__((address_space(3))) void*)l,
      16, 0, 0);
}
__device__ __forceinline__ void vm_wait2() { asm volatile("s_waitcnt vmcnt(2)" ::: "memory"); }
__device__ __forceinline__ void vm_wait0() { asm volatile("s_waitcnt vmcnt(0)" ::: "memory"); }
__device__ __forceinline__ void lgkm0()    { asm volatile("s_waitcnt lgkmcnt(0)" ::: "memory"); }
__device__ __forceinline__ void barrier_() {
  __builtin_amdgcn_s_barrier();
  __builtin_amdgcn_sched_barrier(0);
}

// ---------------------------------------------------------------- 128x128 GEMM
// A: Mx K bf16 (global_load_lds, 3-deep). B: NxK **f32** reg-staged (T14):
// loadB(t+1) at top of iter t -> vmcnt(2) after MFMA -> cvt -> swizzled
// ds_write (2-deep B buffers) -> lgkmcnt(0)+barrier. Per-lane OOB guard.
// Swizzle: 64B rows, phys chunk = data ^ ((row>>1)&3); conflict-free (R4-R7).
__global__ __launch_bounds__(256) void gemm128(
    const u16* __restrict__ A, const float* __restrict__ B,
    float* __restrict__ C, int N, int K, int kslice)
{
  __shared__ alignas(128) u16 As[3 * 4096];
  __shared__ alignas(128) u16 Bs[2 * 4096];
  const int tid = threadIdx.x;
  const int m0 = blockIdx.x << 7;
  const int n0 = blockIdx.y << 7;
  const int lane = tid & 63, wid = tid >> 6;
  const int wm = (wid >> 1) << 6, wn = (wid & 1) << 6;
  const int lr = lane & 15, kg = lane >> 4;
  const int kb = blockIdx.z * kslice;

  // A staging: issue i stages rows i*64 + wid*16 + (lane>>2)
  const int srowA = wid * 16 + (lane >> 2);
  const int scolA = ((lane & 3) ^ ((lane >> 3) & 3)) << 3;
  const u16* gA = A + (size_t)(m0 + srowA) * K + scolA;

  // B staging: thread -> row tid>>1 (0..127), data chunks {bcp, bcp+1} (8 f32 each)
  const int brow = tid >> 1, bcp = (tid & 1) << 1;
  const int bkey = (brow >> 1) & 3;
  const bool bvalid = (n0 + brow) < N;
  const float* gB = B + (size_t)(bvalid ? n0 + brow : 0) * K + kb + (bcp << 3);
  u16* wB0 = &Bs[brow * 32 + ((bcp ^ bkey) << 3)];
  u16* wB1 = &Bs[brow * 32 + (((bcp + 1) ^ bkey) << 3)];

  f32x4 acc[4][4];
#pragma unroll
  for (int i = 0; i < 4; ++i)
#pragma unroll
    for (int j = 0; j < 4; ++j) acc[i][j] = (f32x4){0.f, 0.f, 0.f, 0.f};

  const int nt = kslice >> 5;

  auto stageA = [&](int buf, int t) {
    const int ko = kb + (t << 5);
    gload16(gA + ko,                    &As[buf * 4096 + wid * 512]);
    gload16(gA + ko + (size_t)64 * K,   &As[buf * 4096 + 2048 + wid * 512]);
  };
  f32x4 r0, r1, r2, r3;
  auto loadB = [&](int t) {
    const float* p = gB + (t << 5);
    r0 = *(const f32x4*)(p);     r1 = *(const f32x4*)(p + 4);
    r2 = *(const f32x4*)(p + 8); r3 = *(const f32x4*)(p + 12);
  };
  auto writeB = [&](int t) {
    u16x8 o0, o1;
#pragma unroll
    for (int e = 0; e < 4; ++e) {
      o0[e] = bvalid ? f2bf(r0[e]) : (u16)0; o0[4+e] = bvalid ? f2bf(r1[e]) : (u16)0;
      o1[e] = bvalid ? f2bf(r2[e]) : (u16)0; o1[4+e] = bvalid ? f2bf(r3[e]) : (u16)0;
    }
    *(u16x8*)(wB0 + (t & 1) * 4096) = o0;
    *(u16x8*)(wB1 + (t & 1) * 4096) = o1;
  };

  loadB(0); stageA(0, 0); stageA(1, 1);
  vm_wait2();                    // B0 + A0 done; A1 in flight
  writeB(0); lgkm0(); barrier_();

  const int cxr = (lr >> 1) & 3;
  for (int t = 0; t < nt; ++t) {
    if (t + 1 < nt) loadB(t + 1);
    if (t + 2 < nt) stageA((t + 2) % 3, t + 2);
    bf16x8 af[4], bfr[4];
    const int po = (kg ^ cxr) << 3;
    const int ab = (t % 3) * 4096, bb = (t & 1) * 4096;
#pragma unroll
    for (int f = 0; f < 4; ++f) {
      af[f]  = *(const bf16x8*)&As[ab + (wm + f * 16 + lr) * 32 + po];
      bfr[f] = *(const bf16x8*)&Bs[bb + (wn + f * 16 + lr) * 32 + po];
    }
#pragma unroll
    for (int i = 0; i < 4; ++i)
#pragma unroll
      for (int j = 0; j < 4; ++j)
        acc[i][j] = __builtin_amdgcn_mfma_f32_16x16x32_bf16(af[i], bfr[j], acc[i][j], 0, 0, 0);
    if (t + 1 < nt) {
      if (t + 2 < nt) vm_wait2(); else vm_wait0();
      writeB(t + 1); lgkm0(); barrier_();
    }
  }

  const int mr = (lane >> 4) << 2;
  const int nc = lane & 15;
  float* Cw = C + (gridDim.z > 1 ? (size_t)blockIdx.z * 1024 * N : 0);
#pragma unroll
  for (int i = 0; i < 4; ++i)
#pragma unroll
    for (int j = 0; j < 4; ++j) {
      int n = n0 + wn + j * 16 + nc;
      if (n < N) {
#pragma unroll
        for (int e = 0; e < 4; ++e)
          Cw[(size_t)(m0 + wm + i * 16 + mr + e) * N + n] = acc[i][j][e];
      }
    }
}

// ---------------------------------------------------------------- 256x128 GEMM
// 8 waves, BM=256, BN=128, BK=32; A bf16 gload_lds 3-deep; B f32 reg-staged.
// swz=1 (LM head): 1-D grid 4m x 400n XCD-bijective; lsepart LSE partials;
// per-lane guard row<N zeroes the pad rows. fc1mode: B rows taken from
// y/g halves in 16-row subtile interleave; epilogue emits bf16 y*silu(g).
__global__ __launch_bounds__(512) void gemm256(
    const u16* __restrict__ A, const float* __restrict__ B,
    float* __restrict__ C, int N, int K,
    float* __restrict__ lsepart, int swz, int nblk,
    u16* __restrict__ glu_out, int fc1mode)
{
  __shared__ alignas(128) u16 As[3 * 8192];
  __shared__ alignas(128) u16 Bs[2 * 4096];
  const int tid = threadIdx.x;
  int m0, n0;
  if (swz) {
    int bid = blockIdx.x;
    m0 = ((bid >> 3) & 3) << 8;
    n0 = ((bid & 7) + ((bid >> 5) << 3)) << 7;
  } else {
    m0 = blockIdx.x << 8;
    n0 = blockIdx.y << 7;
  }
  const int lane = tid & 63, wid = tid >> 6;
  const int wm = (wid >> 1) << 6, wn = (wid & 1) << 6;
  const int lr = lane & 15, kg = lane >> 4;

  const int srowA = wid * 16 + (lane >> 2);       // within 128-row issue
  const int scolA = ((lane & 3) ^ ((lane >> 3) & 3)) << 3;
  const u16* gA = A + (size_t)(m0 + srowA) * K + scolA;

  // B: thread -> row tid>>2 (0..127), data chunk tid&3 (8 f32)
  const int brow = tid >> 2, bchunk = tid & 3;
  int bsrc;
  if (fc1mode) {
    int s = brow >> 4, inner = brow & 15;
    bsrc = ((s & 1) << 12) + (n0 >> 1) + ((s >> 1) << 4) + inner;
  } else bsrc = n0 + brow;
  const bool bvalid = bsrc < N;
  const float* gB = B + (size_t)(bvalid ? bsrc : 0) * K + (bchunk << 3);
  u16* wB0 = &Bs[brow * 32 + ((bchunk ^ ((brow >> 1) & 3)) << 3)];

  f32x4 acc[4][4];
#pragma unroll
  for (int i = 0; i < 4; ++i)
#pragma unroll
    for (int j = 0; j < 4; ++j) acc[i][j] = (f32x4){0.f, 0.f, 0.f, 0.f};

  const int nt = K >> 5;

  auto stageA = [&](int buf, int t) {
    const int ko = t << 5;
    gload16(gA + ko,                    &As[buf * 8192 + wid * 512]);
    gload16(gA + ko + (size_t)128 * K,  &As[buf * 8192 + 4096 + wid * 512]);
  };
  f32x4 r0, r1;
  auto loadB = [&](int t) {
    const float* p = gB + (t << 5);
    r0 = *(const f32x4*)(p); r1 = *(const f32x4*)(p + 4);
  };
  auto writeB = [&](int t) {
    u16x8 o;
#pragma unroll
    for (int e = 0; e < 4; ++e) {
      o[e]     = bvalid ? f2bf(r0[e]) : (u16)0;
      o[4 + e] = bvalid ? f2bf(r1[e]) : (u16)0;
    }
    *(u16x8*)(wB0 + (t & 1) * 4096) = o;
  };

  loadB(0); stageA(0, 0); stageA(1, 1);
  vm_wait2();
  writeB(0); lgkm0(); barrier_();

  const int cxr = (lr >> 1) & 3;
  for (int t = 0; t < nt; ++t) {
    if (t + 1 < nt) loadB(t + 1);
    if (t + 2 < nt) stageA((t + 2) % 3, t + 2);
    bf16x8 af[4], bfr[4];
    const int po = (kg ^ cxr) << 3;
    const int ab = (t % 3) * 8192, bb = (t & 1) * 4096;
#pragma unroll
    for (int f = 0; f < 4; ++f) {
      af[f]  = *(const bf16x8*)&As[ab + (wm + f * 16 + lr) * 32 + po];
      bfr[f] = *(const bf16x8*)&Bs[bb + (wn + f * 16 + lr) * 32 + po];
    }
#pragma unroll
    for (int i = 0; i < 4; ++i)
#pragma unroll
      for (int j = 0; j < 4; ++j)
        acc[i][j] = __builtin_amdgcn_mfma_f32_16x16x32_bf16(af[i], bfr[j], acc[i][j], 0, 0, 0);
    if (t + 1 < nt) {
      if (t + 2 < nt) vm_wait2(); else vm_wait0();
      writeB(t + 1); lgkm0(); barrier_();
    }
  }

  const int mr = (lane >> 4) << 2;
  const int nc = lane & 15;

  if (glu_out) {
    // y at even n-subtiles, g at odd; pair (j, j+1) lives in the same thread.
#pragma unroll
    for (int i = 0; i < 4; ++i)
#pragma unroll
      for (int j = 0; j < 4; j += 2)
#pragma unroll
        for (int e = 0; e < 4; ++e) {
          float y = acc[i][j][e], g = acc[i][j + 1][e];
          int q = (n0 >> 1) + (wn >> 1) + ((j >> 1) << 4) + nc;
          int row = m0 + wm + i * 16 + mr + e;
          glu_out[(size_t)row * 4096 + q] = f2bf(y * silu_f(g));
        }
    return;
  }

#pragma unroll
  for (int i = 0; i < 4; ++i)
#pragma unroll
    for (int j = 0; j < 4; ++j) {
      int n = n0 + wn + j * 16 + nc;
      if (n < N) {
#pragma unroll
        for (int e = 0; e < 4; ++e)
          C[(size_t)(m0 + wm + i * 16 + mr + e) * N + n] = acc[i][j][e];
      }
    }

  if (lsepart) {
    __syncthreads();
    float* Ls = (float*)As;    // [256 rows][2 halves][2] = 4KB
#pragma unroll
    for (int i = 0; i < 4; ++i)
#pragma unroll
      for (int e = 0; e < 4; ++e) {
        float pm = -1e30f;
#pragma unroll
        for (int j = 0; j < 4; ++j) {
          int n = n0 + wn + j * 16 + nc;
          if (n < N) pm = fmaxf(pm, acc[i][j][e]);
        }
#pragma unroll
        for (int o = 1; o < 16; o <<= 1) pm = fmaxf(pm, __shfl_xor(pm, o));
        float ps = 0.f;
#pragma unroll
        for (int j = 0; j < 4; ++j) {
          int n = n0 + wn + j * 16 + nc;
          if (n < N) ps += expf(acc[i][j][e] - pm);
        }
#pragma unroll
        for (int o = 1; o < 16; o <<= 1) ps += __shfl_xor(ps, o);
        if (nc == 0) {
          int row = wm + i * 16 + mr + e;
          Ls[row * 4 + (wid & 1) * 2] = pm;
          Ls[row * 4 + (wid & 1) * 2 + 1] = ps;
        }
      }
    __syncthreads();
    if (tid < 256) {
      float pa = Ls[tid * 4], sa = Ls[tid * 4 + 1];
      float pb = Ls[tid * 4 + 2], sb = Ls[tid * 4 + 3];
      float M = fmaxf(pa, pb);
      float S = sa * expf(pa - M) + sb * expf(pb - M);
      ((f32x2*)lsepart)[(size_t)(m0 + tid) * nblk + (n0 >> 7)] = (f32x2){M, S};
    }
  }
}

// ---------------------------------------------------------------- fused LN
__device__ __forceinline__ void ln_write(f32x4 v, const float* __restrict__ w,
                                         u16* __restrict__ out, int t, int tid) {
  float s = v[0] + v[1] + v[2] + v[3];
  float sq = v[0]*v[0] + v[1]*v[1] + v[2]*v[2] + v[3]*v[3];
#pragma unroll
  for (int o = 32; o; o >>= 1) { s += __shfl_down(s, o); sq += __shfl_down(sq, o); }
  __shared__ float sb[4], qb[4];
  if ((tid & 63) == 0) { sb[tid >> 6] = s; qb[tid >> 6] = sq; }
  __syncthreads();
  s = sb[0] + sb[1] + sb[2] + sb[3];
  sq = qb[0] + qb[1] + qb[2] + qb[3];
  float mu = s * (1.f / 1024.f);
  float rstd = rsqrtf(sq * (1.f / 1024.f) - mu * mu + 1e-5f);
  u16x4 o;
#pragma unroll
  for (int e = 0; e < 4; ++e) o[e] = f2bf((v[e] - mu) * rstd * w[tid * 4 + e]);
  ((u16x4*)out)[t * 256 + tid] = o;
}

__global__ void k_ln_embed(const int* __restrict__ idx, const float* __restrict__ E,
                           const float* __restrict__ w, float* __restrict__ hbuf,
                           u16* __restrict__ out) {
  int t = blockIdx.x, tid = threadIdx.x;
  f32x4 v = ((const f32x4*)(E + (size_t)idx[t] * DMODEL))[tid];
  ((f32x4*)hbuf)[t * 256 + tid] = v;
  ln_write(v, w, out, t, tid);
}

__global__ void k_red_ln(const float* __restrict__ part, int S,
                         float* __restrict__ hbuf, const float* __restrict__ w,
                         u16* __restrict__ out) {
  int t = blockIdx.x, tid = threadIdx.x;
  f32x4 v = ((const f32x4*)hbuf)[t * 256 + tid];
  for (int k = 0; k < S; ++k)
    v += ((const f32x4*)part)[(size_t)k * 262144 + t * 256 + tid];
  ((f32x4*)hbuf)[t * 256 + tid] = v;
  ln_write(v, w, out, t, tid);
}

// ---------------------------------------------------------------- conv + dt
__global__ void k_convdt(const float* __restrict__ zx, const float* __restrict__ cw,
                         const float* __restrict__ cb, const float* __restrict__ dtb,
                         const float* __restrict__ alog, float* __restrict__ xbc,
                         float* __restrict__ dtsp, float* __restrict__ dag) {
  int t = blockIdx.y, x = blockIdx.x, tid = threadIdx.x;
  if (x < 8 || tid < 128) {
    int c = x * 256 + tid;
    float acc = cb[c];
#pragma unroll
    for (int k = 0; k < 4; ++k) {
      int tt = t + k - 3;
      if (tt >= 0) acc += zx[(size_t)tt * DPROJ + 2048 + c] * cw[c * 4 + k];
    }
    xbc[(size_t)t * CONVDIM + c] = silu_f(acc);
  } else if (tid < 160) {
    int hh = tid - 128;
    float raw = zx[(size_t)t * DPROJ + 4224 + hh] + dtb[hh];
    float sp = raw > 20.f ? raw : log1pf(expf(raw));
    dtsp[t * 32 + hh] = sp;
    dag[t * 32 + hh] = expf(-expf(alog[hh]) * sp);
  }
}

// ---------------------------------------------------------------- chunked scan
__global__ __launch_bounds__(256) void k_scan_local(
    const float* __restrict__ xbc, const float* __restrict__ dtsp,
    const float* __restrict__ dag, float* __restrict__ yb, float* __restrict__ Sloc,
    float* __restrict__ pref, float* __restrict__ dacum)
{
  int c = blockIdx.x, hh = blockIdx.y;
  int tid = threadIdx.x;
  int p = tid >> 2, ng = tid & 3, n0 = ng << 4;
  float st[16];
#pragma unroll
  for (int j = 0; j < 16; ++j) st[j] = 0.f;
  float P = 1.f;
  for (int s_ = 0; s_ < CLEN; ++s_) {
    int t = c * CLEN + s_;
    float dA = dag[t * 32 + hh];
    P *= dA;
    if (tid == 0) pref[t * 32 + hh] = P;
    float coef = dtsp[t * 32 + hh] * xbc[(size_t)t * CONVDIM + hh * 64 + p];
    const f32x4* B4 = (const f32x4*)&xbc[(size_t)t * CONVDIM + 2048 + n0];
    const f32x4* C4 = (const f32x4*)&xbc[(size_t)t * CONVDIM + 2112 + n0];
    float y = 0.f;
#pragma unroll
    for (int q = 0; q < 4; ++q) {
      f32x4 b = B4[q], cc = C4[q];
#pragma unroll
      for (int e = 0; e < 4; ++e) {
        int j = q * 4 + e;
        st[j] = dA * st[j] + coef * b[e];
        y += st[j] * cc[e];
      }
    }
    y += __shfl_xor(y, 1);
    y += __shfl_xor(y, 2);
    if (ng == 0) yb[(size_t)t * DINNER + hh * 64 + p] = y;
  }
  if (tid == 0) dacum[c * 32 + hh] = P;
  float* Sp = Sloc + ((size_t)(c * 32 + hh) * 64 + p) * 64 + n0;
#pragma unroll
  for (int q = 0; q < 4; ++q)
    *(f32x4*)(Sp + q * 4) = (f32x4){ st[q*4], st[q*4+1], st[q*4+2], st[q*4+3] };
}

__global__ void k_chain(const float* __restrict__ Sloc, const float* __restrict__ dacum,
                        float* __restrict__ Sin) {
  int e = blockIdx.x * 256 + threadIdx.x;  // 131072
  int hh = e >> 12;
  float S = 0.f;
  for (int c = 0; c < NCHUNK; c += 8) {
    float sl[8], dd[8];
#pragma unroll
    for (int j = 0; j < 8; ++j) sl[j] = Sloc[(size_t)(c + j) * 131072 + e];
#pragma unroll
    for (int j = 0; j < 8; ++j) dd[j] = dacum[(c + j) * 32 + hh];
#pragma unroll
    for (int j = 0; j < 8; ++j) {
      Sin[(size_t)(c + j) * 131072 + e] = S;
      S = dd[j] * S + sl[j];
    }
  }
}

__global__ __launch_bounds__(256) void k_scan_fix(
    const float* __restrict__ xbc, const float* __restrict__ pref,
    const float* __restrict__ Sin, const float* __restrict__ Dp,
    float* __restrict__ yb)
{
  __shared__ float Sl[64 * 68];
  int c = blockIdx.x, hh = blockIdx.y;
  int tid = threadIdx.x;
  for (int i = 0; i < 16; ++i) {
    int e = i * 256 + tid;
    Sl[(e >> 6) * 68 + (e & 63)] = Sin[(size_t)(c * 32 + hh) * 4096 + e];
  }
  __syncthreads();
  int p = tid >> 2, ng = tid & 3, n0 = ng << 4;
  float Dh = Dp[hh];
  for (int s_ = 0; s_ < CLEN; ++s_) {
    int t = c * CLEN + s_;
    const f32x4* C4 = (const f32x4*)&xbc[(size_t)t * CONVDIM + 2112 + n0];
    float yc = 0.f;
#pragma unroll
    for (int q = 0; q < 4; ++q) {
      f32x4 cc = C4[q];
#pragma unroll
      for (int e = 0; e < 4; ++e) yc += Sl[p * 68 + n0 + q * 4 + e] * cc[e];
    }
    yc += __shfl_xor(yc, 1);
    yc += __shfl_xor(yc, 2);
    if (ng == 0) {
      size_t oy = (size_t)t * DINNER + hh * 64 + p;
      yb[oy] = yb[oy] + pref[t * 32 + hh] * yc + Dh * xbc[(size_t)t * CONVDIM + hh * 64 + p];
    }
  }
}

__global__ void k_gated_rms(const float* __restrict__ yb, const float* __restrict__ zx,
                            const float* __restrict__ gw, u16* __restrict__ out) {
  int t = blockIdx.x, tid = threadIdx.x;
  float v[8], ss = 0.f;
#pragma unroll
  for (int i = 0; i < 8; ++i) {
    int j = tid + i * 256;
    float z = zx[(size_t)t * DPROJ + j];
    float vv = yb[(size_t)t * DINNER + j] * silu_f(z);
    v[i] = vv; ss += vv * vv;
  }
#pragma unroll
  for (int o = 32; o; o >>= 1) ss += __shfl_down(ss, o);
  __shared__ float sb[4];
  if ((tid & 63) == 0) sb[tid >> 6] = ss;
  __syncthreads();
  ss = sb[0] + sb[1] + sb[2] + sb[3];
  float rstd = rsqrtf(ss * (1.f / 2048.f) + 1e-5f);
#pragma unroll
  for (int i = 0; i < 8; ++i) {
    int j = tid + i * 256;
    out[(size_t)t * DINNER + j] = f2bf(v[i] * rstd * gw[j]);
  }
}

// ---------------------------------------------------------------- loss
__global__ void k_loss_final(const float* __restrict__ lsepart,
                             const float* __restrict__ logits,
                             const int* __restrict__ tgt, float* __restrict__ part) {
  int t = blockIdx.x, tid = threadIdx.x;
  float m = -1e30f, s = 0.f;
  for (int nb = tid; nb < NBLK_V; nb += 256) {
    f32x2 v = ((const f32x2*)lsepart)[(size_t)t * NBLK_V + nb];
    float M = fmaxf(m, v[0]);
    s = s * expf(m - M) + v[1] * expf(v[0] - M);
    m = M;
  }
#pragma unroll
  for (int o = 32; o; o >>= 1) {
    float m2 = __shfl_down(m, o), s2 = __shfl_down(s, o);
    float M = fmaxf(m, m2);
    s = s * expf(m - M) + s2 * expf(m2 - M);
    m = M;
  }
  __shared__ float ms[4], ssh[4];
  if ((tid & 63) == 0) { ms[tid >> 6] = m; ssh[tid >> 6] = s; }
  __syncthreads();
  if (tid == 0) {
    float M = ms[0], S = ssh[0];
    for (int w = 1; w < 4; ++w) {
      float M2 = fmaxf(M, ms[w]);
      S = S * expf(M - M2) + ssh[w] * expf(ms[w] - M2);
      M = M2;
    }
    part[t] = (M + logf(S)) - logits[(size_t)t * VOCAB + tgt[t]];
  }
}

__global__ void k_loss_mean(const float* __restrict__ part, float* __restrict__ out) {
  int tid = threadIdx.x;
  float s = 0.f;
  for (int j = tid; j < 1024; j += 256) s += part[j];
#pragma unroll
  for (int o = 32; o; o >>= 1) s += __shfl_down(s, o);
  __shared__ float sb[4];
  if ((tid & 63) == 0) sb[tid >> 6] = s;
  __syncthreads();
  if (tid == 0) out[0] = (sb[0] + sb[1] + sb[2] + sb[3]) * (1.f / 1024.f);
}

// ---------------------------------------------------------------- launch
extern "C" void kernel_launch(void* const* d_in, const int* in_sizes, int n_in,
                              void* d_out, int out_size, void* d_ws, size_t ws_size,
                              hipStream_t stream)
{
  const int*   idx       = (const int*)d_in[0];
  const int*   tgt       = (const int*)d_in[1];
  const float* E         = (const float*)d_in[2];
  const float* norm_w    = (const float*)d_in[3];
  const float* norm2_w   = (const float*)d_in[4];
  const float* in_proj_w = (const float*)d_in[5];
  const float* conv_w    = (const float*)d_in[6];
  const float* conv_b    = (const float*)d_in[7];
  const float* dt_bias   = (const float*)d_in[8];
  const float* A_log     = (const float*)d_in[9];
  const float* Dp        = (const float*)d_in[10];
  const float* gnorm_w   = (const float*)d_in[11];
  const float* out_proj_w= (const float*)d_in[12];
  const float* fc1_w     = (const float*)d_in[13];
  const float* fc2_w     = (const float*)d_in[14];
  const float* norm_f_w  = (const float*)d_in[15];
  float* logits = (float*)d_out;
  (void)in_sizes; (void)n_in; (void)out_size; (void)ws_size;

  char* W = (char*)d_ws;
  size_t off = 0;
  auto A8 = [&](size_t bytes) { void* p = W + off; off = (off + bytes + 255) & ~(size_t)255; return p; };
  float* hbuf   = (float*)A8((size_t)1024 * 1024 * 4);
  u16*   xnormb = (u16*)  A8((size_t)1024 * 1024 * 2);
  u16*   gatedb = (u16*)  A8((size_t)1024 * 2048 * 2);
  u16*   glub   = (u16*)  A8((size_t)1024 * 4096 * 2);
  float* dtsp   = (float*)A8((size_t)1024 * 32 * 4);
  float* dag    = (float*)A8((size_t)1024 * 32 * 4);
  float* pref   = (float*)A8((size_t)1024 * 32 * 4);
  float* dacum  = (float*)A8((size_t)2048 * 4);
  float* lpart  = (float*)A8((size_t)1024 * 4);
  float* lsebuf = (float*)A8((size_t)1024 * NBLK_V * 2 * 4);
  // layer temporaries
  float* big0   = (float*)A8((size_t)1024 * DPROJ * 4);      // 17.4 MB
  float* xbc    = (float*)A8((size_t)1024 * CONVDIM * 4);    // 8.9 MB
  float* yb     = (float*)A8((size_t)1024 * DINNER * 4);     // 8 MB
  float* Sloc   = (float*)A8((size_t)32 * 1024 * 1024);      // scan / splitK alias
  float* Sin    = (float*)A8((size_t)16 * 1024 * 1024);
  float* part   = Sloc;   // 8 splitK slices x 4 MB (scan buffers dead then)

  dim3 b256(256), b512(512);

  k_ln_embed<<<1024, b256, 0, stream>>>(idx, E, norm_w, hbuf, xnormb);

  const float* nw_next[2] = { norm_w + 1024, norm_f_w };
  for (int L = 0; L < 2; ++L) {
    gemm128<<<dim3(8, 34, 1), b256, 0, stream>>>(
        xnormb, in_proj_w + (size_t)L * DPROJ * 1024, big0, DPROJ, 1024, 1024);
    k_convdt<<<dim3(9, 1024), b256, 0, stream>>>(
        big0, conv_w + L * CONVDIM * 4, conv_b + L * CONVDIM,
        dt_bias + L * 32, A_log + L * 32, xbc, dtsp, dag);
    k_scan_local<<<dim3(NCHUNK, 32), b256, 0, stream>>>(xbc, dtsp, dag, yb, Sloc, pref, dacum);
    k_chain<<<512, b256, 0, stream>>>(Sloc, dacum, Sin);
    k_scan_fix<<<dim3(NCHUNK, 32), b256, 0, stream>>>(xbc, pref, Sin, Dp + L * 32, yb);
    k_gated_rms<<<1024, b256, 0, stream>>>(yb, big0, gnorm_w + L * 2048, gatedb);
    gemm128<<<dim3(8, 8, 4), b256, 0, stream>>>(
        gatedb, out_proj_w + (size_t)L * 1024 * 2048, part, 1024, 2048, 512);
    k_red_ln<<<1024, b256, 0, stream>>>(part, 4, hbuf, norm2_w + L * 1024, xnormb);
    gemm256<<<dim3(4, 64, 1), b512, 0, stream>>>(
        xnormb, fc1_w + (size_t)L * 8192 * 1024, nullptr, 8192, 1024,
        nullptr, 0, 64, glub, 1);
    gemm128<<<dim3(8, 8, 8), b256, 0, stream>>>(
        glub, fc2_w + (size_t)L * 1024 * 4096, part, 1024, 4096, 512);
    k_red_ln<<<1024, b256, 0, stream>>>(part, 8, hbuf, nw_next[L], xnormb);
  }

  gemm256<<<dim3(4 * NBLK_V, 1, 1), b512, 0, stream>>>(
      xnormb, E, logits, VOCAB, 1024, lsebuf, 1, NBLK_V, nullptr, 0);
  k_loss_final<<<1024, b256, 0, stream>>>(lsebuf, logits, tgt, lpart);
  k_loss_mean<<<1, b256, 0, stream>>>(lpart, logits + (size_t)1024 * VOCAB);
}